// Round 1
// 94.525 us; speedup vs baseline: 1.0381x; 1.0381x over previous
//
#include <hip/hip_runtime.h>
#include <float.h>

#define B_ 4
#define C_ 128
#define H_ 128
#define W_ 128
#define WL_ 32
#define NL_ 1024   // 32*32 low-res cells

// ---------------------------------------------------------------------------
// Kernel A: stable top-2 + 2-way softmax per attention row. One wave per row,
// 4 rows per 256-thread block. Unchanged (verified) reduction logic.
// ---------------------------------------------------------------------------
__global__ __launch_bounds__(256) void k_top2(const float* __restrict__ attn,
                                              int2* __restrict__ tmap,
                                              float2* __restrict__ wmap) {
    int lane = threadIdx.x & 63;
    int wv   = threadIdx.x >> 6;
    int row  = blockIdx.x * 4 + wv;          // 0..4095 (b*1024 + q)
    const float4* p = (const float4*)(attn + (size_t)row * NL_);

    float v0 = -FLT_MAX, v1 = -FLT_MAX;
    int   i0 = 0x7fffffff, i1 = 0x7fffffff;

    #pragma unroll
    for (int s = 0; s < 4; ++s) {
        float4 u = p[lane + 64 * s];
        int j = 4 * (lane + 64 * s);        // strictly increasing per lane
        float vals[4] = {u.x, u.y, u.z, u.w};
        #pragma unroll
        for (int t = 0; t < 4; ++t) {
            float a = vals[t];
            int   ji = j + t;
            if (a > v0)      { v1 = v0; i1 = i0; v0 = a; i0 = ji; }
            else if (a > v1) { v1 = a; i1 = ji; }
        }
    }

    #pragma unroll
    for (int off = 32; off >= 1; off >>= 1) {
        float ov0 = __shfl_xor(v0, off, 64);
        int   oi0 = __shfl_xor(i0, off, 64);
        float ov1 = __shfl_xor(v1, off, 64);
        int   oi1 = __shfl_xor(i1, off, 64);
        bool a_first = (v0 > ov0) || (v0 == ov0 && i0 < oi0);
        float n0, n1; int m0, m1;
        if (a_first) {
            n0 = v0; m0 = i0;
            bool s2 = (v1 > ov0) || (v1 == ov0 && i1 < oi0);
            n1 = s2 ? v1 : ov0; m1 = s2 ? i1 : oi0;
        } else {
            n0 = ov0; m0 = oi0;
            bool s2 = (v0 > ov1) || (v0 == ov1 && i0 < oi1);
            n1 = s2 ? v0 : ov1; m1 = s2 ? i0 : oi1;
        }
        v0 = n0; i0 = m0; v1 = n1; i1 = m1;
    }

    if (lane == 0) {
        float e  = expf(v1 - v0);            // v1 <= v0, safe
        float w0 = 1.f / (1.f + e);
        tmap[row] = make_int2(i0, i1);
        wmap[row] = make_float2(w0, 1.f - w0);
    }
}

// ---------------------------------------------------------------------------
// Kernel B (fused): one 1024-thread block per (b,c) plane.
//   Phase 1: each thread sums one 4x4 block of v -> LDS S_l[1024] (coalesced
//            512B-per-half-wave row loads, conflict-free LDS store).
//   Phase 2: each thread combines its cell's top-2 via LDS gathers and writes
//            the constant 4x4 output tile (4 x float4, 512B contiguous per
//            half-wave per row).
// S never touches global memory; tmap/wmap (64 KB total) stay L2-resident.
// 512 blocks x 1024 threads = 2 blocks/CU = full thread occupancy.
// ---------------------------------------------------------------------------
__global__ __launch_bounds__(1024) void k_plane(const float* __restrict__ v,
                                                const int2* __restrict__ tmap,
                                                const float2* __restrict__ wmap,
                                                float* __restrict__ out) {
    __shared__ float S_l[NL_];
    int plane = blockIdx.x;                  // b*C_ + c
    int b   = plane >> 7;
    int tid = threadIdx.x;                   // == cell, 0..1023

    // phase 1: block-sum into LDS (identical arithmetic to previous version)
    {
        int cr = tid >> 5, cc = tid & 31;
        const float* rp = v + (size_t)plane * (H_ * W_) + (cr * 4) * W_ + cc * 4;
        float s = 0.f;
        #pragma unroll
        for (int r = 0; r < 4; ++r) {
            float4 u = *(const float4*)(rp + r * W_);
            s += u.x + u.y + u.z + u.w;
        }
        S_l[tid] = s;                        // lane -> word: conflict-free
    }
    __syncthreads();

    // phase 2: combine + write 4x4 tile
    {
        int2   t = tmap[b * NL_ + tid];      // coalesced 8B, L2-resident
        float2 w = wmap[b * NL_ + tid];
        float val = (w.x * S_l[t.x] + w.y * S_l[t.y]) * 0.0625f;

        int ht = tid >> 5, wb = tid & 31;
        float4 o4 = make_float4(val, val, val, val);
        float* op = out + ((size_t)plane * H_ + ht * 4) * W_ + wb * 4;
        #pragma unroll
        for (int r = 0; r < 4; ++r)
            *(float4*)(op + r * W_) = o4;    // 4 rows of the 4x4 tile
    }
}

extern "C" void kernel_launch(void* const* d_in, const int* in_sizes, int n_in,
                              void* d_out, int out_size, void* d_ws, size_t ws_size,
                              hipStream_t stream) {
    const float* v    = (const float*)d_in[0];   // fp32 (B,C,H,W)
    const float* attn = (const float*)d_in[1];   // fp32 (B,1024,1024)
    float* out = (float*)d_out;                  // fp32 (B,C,H,W)

    char* base = (char*)d_ws;
    int2*   tmap = (int2*)base;                          // 32 KB
    float2* wmap = (float2*)(base + 4096 * sizeof(int2)); // 32 KB

    k_top2<<<1024, 256, 0, stream>>>(attn, tmap, wmap);
    k_plane<<<B_ * C_, 1024, 0, stream>>>(v, tmap, wmap, out);
}